// Round 3
// baseline (794.006 us; speedup 1.0000x reference)
//
#include <hip/hip_runtime.h>
#include <math.h>

#define Bq 128
#define Nn 8
#define LQ 32
#define LD 256
#define DD 128
#define EPSN 1e-12f
#define NEGV (-9999.0f)

// ---------------- Kernel 1: normalize q rows over D ----------------
__global__ __launch_bounds__(256) void qnorm_k(const float* __restrict__ q,
                                               float* __restrict__ qn) {
    int row  = blockIdx.x * 4 + (threadIdx.x >> 6);   // 4096 rows total
    int lane = threadIdx.x & 63;
    size_t base = (size_t)row * DD + lane * 2;
    float2 v = *reinterpret_cast<const float2*>(q + base);
    float ss = v.x * v.x + v.y * v.y;
#pragma unroll
    for (int o = 32; o; o >>= 1) ss += __shfl_xor(ss, o);
    float inv = 1.0f / fmaxf(sqrtf(ss), EPSN);
    float2 o2; o2.x = v.x * inv; o2.y = v.y * inv;
    *reinterpret_cast<float2*>(qn + base) = o2;
}

// ---------------- Kernel 2: MaxSim scores ----------------
// grid = Nn * Bq blocks; block handles one (n, b) for BOTH tensors.
// Thread t owns d-row t of d_cq[n,b] and d_orig[n,b] (same q, same mask).
// d-rows are read in FULL 128B line batches (8 contiguous float4) -- round 1
// proved this gives zero HBM overfetch; round 2 proved 16B rolling loads
// cause 3.2x refetch. q comes from LDS via wave-uniform ds_read_b128
// (broadcast); each q read feeds 8 FMAs (2 tensors x 4 k).
__global__ __launch_bounds__(256) void maxsim_k(const float* __restrict__ d_cq,
                                                const float* __restrict__ d_orig,
                                                const int* __restrict__ mask,
                                                const float* __restrict__ qn,
                                                float* __restrict__ scores) {
    __shared__ float q_lds[LQ][DD];   // 16 KB
    __shared__ float wm[2][4][LQ];

    int nb = blockIdx.x;              // n*Bq + b, [0,1024)
    int b  = nb & 127;
    int n  = nb >> 7;
    int tid = threadIdx.x;

    // stage q[b] -> LDS, coalesced float4
    {
        const float4* src = reinterpret_cast<const float4*>(qn + (size_t)b * LQ * DD);
        float4* dst = reinterpret_cast<float4*>(&q_lds[0][0]);
#pragma unroll
        for (int i = 0; i < 4; ++i)
            dst[tid + 256 * i] = src[tid + 256 * i];
    }
    __syncthreads();

    const float4* p0 = reinterpret_cast<const float4*>(
        d_cq   + (size_t)nb * LD * DD + (size_t)tid * DD);
    const float4* p1 = reinterpret_cast<const float4*>(
        d_orig + (size_t)nb * LD * DD + (size_t)tid * DD);

    float acc0[LQ], acc1[LQ];
#pragma unroll
    for (int i = 0; i < LQ; ++i) { acc0[i] = 0.0f; acc1[i] = 0.0f; }
    float ssq0 = 0.0f, ssq1 = 0.0f;

#pragma unroll 1
    for (int c = 0; c < 4; ++c) {     // 4 line-chunks of 32 floats (128B)
        float4 a[8], e[8];
#pragma unroll
        for (int i = 0; i < 8; ++i) a[i] = p0[c * 8 + i];
#pragma unroll
        for (int i = 0; i < 8; ++i) e[i] = p1[c * 8 + i];
#pragma unroll
        for (int i = 0; i < 8; ++i) {
            ssq0 += a[i].x * a[i].x + a[i].y * a[i].y + a[i].z * a[i].z + a[i].w * a[i].w;
            ssq1 += e[i].x * e[i].x + e[i].y * e[i].y + e[i].z * e[i].z + e[i].w * e[i].w;
        }
#pragma unroll
        for (int kq = 0; kq < 8; ++kq) {
            float4 av = a[kq], ev = e[kq];
#pragma unroll
            for (int lq = 0; lq < LQ; ++lq) {
                float4 qv = *reinterpret_cast<const float4*>(
                    &q_lds[lq][c * 32 + kq * 4]);   // uniform -> broadcast
                acc0[lq] += qv.x * av.x + qv.y * av.y + qv.z * av.z + qv.w * av.w;
                acc1[lq] += qv.x * ev.x + qv.y * ev.y + qv.z * ev.z + qv.w * ev.w;
            }
        }
    }

    int mk0 = mask[(size_t)nb * LD + tid];   // same mask for both tensors
    float inv0 = 1.0f / fmaxf(sqrtf(ssq0), EPSN);
    float inv1 = 1.0f / fmaxf(sqrtf(ssq1), EPSN);

    int lane = tid & 63, wv = tid >> 6;
    float sel0 = NEGV, sel1 = NEGV;
#pragma unroll
    for (int lq = 0; lq < LQ; ++lq) {
        float s0 = mk0 ? acc0[lq] * inv0 : NEGV;
        float s1 = mk0 ? acc1[lq] * inv1 : NEGV;
#pragma unroll
        for (int o = 32; o; o >>= 1) {
            s0 = fmaxf(s0, __shfl_xor(s0, o));
            s1 = fmaxf(s1, __shfl_xor(s1, o));
        }
        if ((lane & 31) == lq) { sel0 = s0; sel1 = s1; }
    }
    if (lane < 32) { wm[0][wv][lane] = sel0; wm[1][wv][lane] = sel1; }
    __syncthreads();

    if (tid < 64) {
        int g = tid >> 5, l = tid & 31;   // g: 0=cq, 1=orig
        float v = fmaxf(fmaxf(wm[g][0][l], wm[g][1][l]),
                        fmaxf(wm[g][2][l], wm[g][3][l]));
#pragma unroll
        for (int o = 16; o; o >>= 1) v += __shfl_xor(v, o, 32);
        if (l == 0)
            scores[g * (Bq * Nn) + b * Nn + n] = v;
    }
}

// ---------------- Kernel 3: log_softmax + KL ----------------
__global__ void loss_k(const float* __restrict__ scores, float* __restrict__ out) {
    int tid = threadIdx.x;   // 128 threads, one per b
    const float* s = scores + tid * Nn;            // student (cq)
    const float* t = scores + Bq * Nn + tid * Nn;  // teacher (orig)
    float sv[Nn], tv[Nn];
#pragma unroll
    for (int n = 0; n < Nn; ++n) { sv[n] = s[n]; tv[n] = t[n]; }
    float ms = sv[0], mt = tv[0];
#pragma unroll
    for (int n = 1; n < Nn; ++n) { ms = fmaxf(ms, sv[n]); mt = fmaxf(mt, tv[n]); }
    float es = 0.0f, et = 0.0f;
#pragma unroll
    for (int n = 0; n < Nn; ++n) { es += expf(sv[n] - ms); et += expf(tv[n] - mt); }
    float lses = ms + logf(es);
    float lset = mt + logf(et);
    double kl = 0.0;
#pragma unroll
    for (int n = 0; n < Nn; ++n) {
        float lt = tv[n] - lset;
        float ls = sv[n] - lses;
        kl += (double)expf(lt) * ((double)lt - (double)ls);
    }
#pragma unroll
    for (int o = 32; o; o >>= 1) kl += __shfl_xor(kl, o);
    __shared__ double part[2];
    if ((tid & 63) == 0) part[tid >> 6] = kl;
    __syncthreads();
    if (tid == 0) out[0] = (float)((part[0] + part[1]) / (double)Bq);
}

extern "C" void kernel_launch(void* const* d_in, const int* in_sizes, int n_in,
                              void* d_out, int out_size, void* d_ws, size_t ws_size,
                              hipStream_t stream) {
    const float* q     = (const float*)d_in[0];
    const float* dcq   = (const float*)d_in[1];
    const float* dorig = (const float*)d_in[2];
    const int*   mask  = (const int*)d_in[3];
    // labels (d_in[4]) unused by the reference loss path

    float* qn     = (float*)d_ws;                      // [B*LQ*DD] = 2MB
    float* scores = qn + (size_t)Bq * LQ * DD;         // [2][B][N] = 8KB

    qnorm_k<<<(Bq * LQ) / 4, 256, 0, stream>>>(q, qn);
    maxsim_k<<<Nn * Bq, 256, 0, stream>>>(dcq, dorig, mask, qn, scores);
    loss_k<<<1, 128, 0, stream>>>(scores, (float*)d_out);
}

// Round 4
// 204.821 us; speedup vs baseline: 3.8766x; 3.8766x over previous
//
#include <hip/hip_runtime.h>
#include <math.h>

#define Bq 128
#define Nn 8
#define LQ 32
#define LD 256
#define DD 128
#define EPSN 1e-12f
#define NEGV (-9999.0f)

// ---------------- Kernel 1: normalize q rows over D ----------------
__global__ __launch_bounds__(256) void qnorm_k(const float* __restrict__ q,
                                               float* __restrict__ qn) {
    int row  = blockIdx.x * 4 + (threadIdx.x >> 6);   // 4096 rows total
    int lane = threadIdx.x & 63;
    size_t base = (size_t)row * DD + lane * 2;
    float2 v = *reinterpret_cast<const float2*>(q + base);
    float ss = v.x * v.x + v.y * v.y;
#pragma unroll
    for (int o = 32; o; o >>= 1) ss += __shfl_xor(ss, o);
    float inv = 1.0f / fmaxf(sqrtf(ss), EPSN);
    float2 o2; o2.x = v.x * inv; o2.y = v.y * inv;
    *reinterpret_cast<float2*>(qn + base) = o2;
}

// ---------------- Kernel 2: MaxSim scores ----------------
// grid = Nn*Bq blocks; block = one (n,b), BOTH tensors (shared q + mask, so
// each uniform q ds_read_b128 feeds 8 FMAs). Thread t owns d-row t of both.
// d consumed in 64B batches (4 contiguous float4/row, named vars -> no
// runtime indexing/scratch). sched_barrier(0) fences every ~32 ds_reads to
// stop the round-3 hoist/spill (round 2 proved 32-read bodies stay at 72 VGPR).
__global__ __launch_bounds__(256) void maxsim_k(const float* __restrict__ d_cq,
                                                const float* __restrict__ d_orig,
                                                const int* __restrict__ mask,
                                                const float* __restrict__ qn,
                                                float* __restrict__ scores) {
    __shared__ float q_lds[LQ][DD];   // 16 KB
    __shared__ float wm[2][4][LQ];

    int nb = blockIdx.x;              // n*Bq + b
    int b  = nb & 127;
    int n  = nb >> 7;
    int tid = threadIdx.x;

    {   // stage q[b] -> LDS, coalesced float4
        const float4* src = reinterpret_cast<const float4*>(qn + (size_t)b * LQ * DD);
        float4* dst = reinterpret_cast<float4*>(&q_lds[0][0]);
#pragma unroll
        for (int i = 0; i < 4; ++i)
            dst[tid + 256 * i] = src[tid + 256 * i];
    }
    __syncthreads();

    const float4* p0 = reinterpret_cast<const float4*>(
        d_cq   + (size_t)nb * LD * DD + (size_t)tid * DD);
    const float4* p1 = reinterpret_cast<const float4*>(
        d_orig + (size_t)nb * LD * DD + (size_t)tid * DD);

    float acc0[LQ], acc1[LQ];
#pragma unroll
    for (int i = 0; i < LQ; ++i) { acc0[i] = 0.0f; acc1[i] = 0.0f; }
    float ssq0 = 0.0f, ssq1 = 0.0f;

#define QSTEP(AV, EV, JOFF)                                                   \
    {                                                                         \
        ssq0 += AV.x*AV.x + AV.y*AV.y + AV.z*AV.z + AV.w*AV.w;                \
        ssq1 += EV.x*EV.x + EV.y*EV.y + EV.z*EV.z + EV.w*EV.w;                \
        _Pragma("unroll")                                                     \
        for (int lq = 0; lq < LQ; ++lq) {                                     \
            float4 qv = *reinterpret_cast<const float4*>(                     \
                &q_lds[lq][h * 16 + (JOFF)]);  /* wave-uniform -> broadcast */ \
            acc0[lq] += qv.x*AV.x + qv.y*AV.y + qv.z*AV.z + qv.w*AV.w;        \
            acc1[lq] += qv.x*EV.x + qv.y*EV.y + qv.z*EV.z + qv.w*EV.w;        \
        }                                                                     \
    }

#pragma unroll 1
    for (int h = 0; h < 8; ++h) {     // 8 x 64B batches per row
        const float4* pa = p0 + h * 4;
        const float4* pe = p1 + h * 4;
        float4 a0 = pa[0], a1 = pa[1], a2 = pa[2], a3 = pa[3];
        float4 e0 = pe[0], e1 = pe[1], e2 = pe[2], e3 = pe[3];
        QSTEP(a0, e0, 0);
        __builtin_amdgcn_sched_barrier(0);
        QSTEP(a1, e1, 4);
        __builtin_amdgcn_sched_barrier(0);
        QSTEP(a2, e2, 8);
        __builtin_amdgcn_sched_barrier(0);
        QSTEP(a3, e3, 12);
    }
#undef QSTEP

    int mk0 = mask[(size_t)nb * LD + tid];   // same mask for both tensors
    float inv0 = 1.0f / fmaxf(sqrtf(ssq0), EPSN);
    float inv1 = 1.0f / fmaxf(sqrtf(ssq1), EPSN);

    int lane = tid & 63, wv = tid >> 6;
    float sel0 = NEGV, sel1 = NEGV;
#pragma unroll
    for (int lq = 0; lq < LQ; ++lq) {
        float s0 = mk0 ? acc0[lq] * inv0 : NEGV;
        float s1 = mk0 ? acc1[lq] * inv1 : NEGV;
#pragma unroll
        for (int o = 32; o; o >>= 1) {
            s0 = fmaxf(s0, __shfl_xor(s0, o));
            s1 = fmaxf(s1, __shfl_xor(s1, o));
        }
        if ((lane & 31) == lq) { sel0 = s0; sel1 = s1; }
    }
    if (lane < 32) { wm[0][wv][lane] = sel0; wm[1][wv][lane] = sel1; }
    __syncthreads();

    if (tid < 64) {
        int g = tid >> 5, l = tid & 31;   // g: 0=cq(student), 1=orig(teacher)
        float v = fmaxf(fmaxf(wm[g][0][l], wm[g][1][l]),
                        fmaxf(wm[g][2][l], wm[g][3][l]));
#pragma unroll
        for (int o = 16; o; o >>= 1) v += __shfl_xor(v, o, 32);
        if (l == 0)
            scores[g * (Bq * Nn) + b * Nn + n] = v;
    }
}

// ---------------- Kernel 3: log_softmax + KL ----------------
__global__ void loss_k(const float* __restrict__ scores, float* __restrict__ out) {
    int tid = threadIdx.x;   // 128 threads, one per b
    const float* s = scores + tid * Nn;            // student (cq)
    const float* t = scores + Bq * Nn + tid * Nn;  // teacher (orig)
    float sv[Nn], tv[Nn];
#pragma unroll
    for (int n = 0; n < Nn; ++n) { sv[n] = s[n]; tv[n] = t[n]; }
    float ms = sv[0], mt = tv[0];
#pragma unroll
    for (int n = 1; n < Nn; ++n) { ms = fmaxf(ms, sv[n]); mt = fmaxf(mt, tv[n]); }
    float es = 0.0f, et = 0.0f;
#pragma unroll
    for (int n = 0; n < Nn; ++n) { es += expf(sv[n] - ms); et += expf(tv[n] - mt); }
    float lses = ms + logf(es);
    float lset = mt + logf(et);
    double kl = 0.0;
#pragma unroll
    for (int n = 0; n < Nn; ++n) {
        float lt = tv[n] - lset;
        float ls = sv[n] - lses;
        kl += (double)expf(lt) * ((double)lt - (double)ls);
    }
#pragma unroll
    for (int o = 32; o; o >>= 1) kl += __shfl_xor(kl, o);
    __shared__ double part[2];
    if ((tid & 63) == 0) part[tid >> 6] = kl;
    __syncthreads();
    if (tid == 0) out[0] = (float)((part[0] + part[1]) / (double)Bq);
}

extern "C" void kernel_launch(void* const* d_in, const int* in_sizes, int n_in,
                              void* d_out, int out_size, void* d_ws, size_t ws_size,
                              hipStream_t stream) {
    const float* q     = (const float*)d_in[0];
    const float* dcq   = (const float*)d_in[1];
    const float* dorig = (const float*)d_in[2];
    const int*   mask  = (const int*)d_in[3];
    // labels (d_in[4]) unused by the reference loss path

    float* qn     = (float*)d_ws;                      // [B*LQ*DD] = 2MB
    float* scores = qn + (size_t)Bq * LQ * DD;         // [2][B][N] = 8KB

    qnorm_k<<<(Bq * LQ) / 4, 256, 0, stream>>>(q, qn);
    maxsim_k<<<Nn * Bq, 256, 0, stream>>>(dcq, dorig, mask, qn, scores);
    loss_k<<<1, 128, 0, stream>>>(scores, (float*)d_out);
}

// Round 5
// 129.172 us; speedup vs baseline: 6.1469x; 1.5856x over previous
//
#include <hip/hip_runtime.h>
#include <math.h>

#define Bq 128
#define Nn 8
#define LQ 32
#define LD 256
#define DD 128
#define EPSN 1e-12f
#define NEGV (-9999.0f)

// ---------------- Kernel 1: normalize q rows over D ----------------
__global__ __launch_bounds__(256) void qnorm_k(const float* __restrict__ q,
                                               float* __restrict__ qn) {
    int row  = blockIdx.x * 4 + (threadIdx.x >> 6);   // 4096 rows total
    int lane = threadIdx.x & 63;
    size_t base = (size_t)row * DD + lane * 2;
    float2 v = *reinterpret_cast<const float2*>(q + base);
    float ss = v.x * v.x + v.y * v.y;
#pragma unroll
    for (int o = 32; o; o >>= 1) ss += __shfl_xor(ss, o);
    float inv = 1.0f / fmaxf(sqrtf(ss), EPSN);
    float2 o2; o2.x = v.x * inv; o2.y = v.y * inv;
    *reinterpret_cast<float2*>(qn + base) = o2;
}

// ---------------- Kernel 2: MaxSim scores ----------------
// grid = Nn*Bq blocks x 512 threads; block = one (n,b), both tensors.
// Thread t owns d-row (t>>1) of tensor (t&1): even lanes=cq, odd=orig.
//  - 32 accs + 16 staging regs -> ~80 VGPR (round 2 proved 1-tensor fits 72)
//  - q read from LDS at wave-UNIFORM addresses (both parities same chunk)
//  - d consumed in 64B batches (round 4: 139MB fetch), sched_barrier fenced
__global__ __launch_bounds__(512) void maxsim_k(const float* __restrict__ d_cq,
                                                const float* __restrict__ d_orig,
                                                const int* __restrict__ mask,
                                                const float* __restrict__ qn,
                                                float* __restrict__ scores) {
    __shared__ float q_lds[LQ][DD];   // 16 KB
    __shared__ float wm[8][64];       // 2 KB

    int nb = blockIdx.x;              // n*Bq + b
    int b  = nb & 127;
    int n  = nb >> 7;
    int tid = threadIdx.x;

    {   // stage q[b] -> LDS, coalesced float4 (512 thr x 2 = 1024 float4)
        const float4* src = reinterpret_cast<const float4*>(qn + (size_t)b * LQ * DD);
        float4* dst = reinterpret_cast<float4*>(&q_lds[0][0]);
        dst[tid]       = src[tid];
        dst[tid + 512] = src[tid + 512];
    }
    __syncthreads();

    int row    = tid >> 1;
    int parity = tid & 1;             // 0 = cq (student), 1 = orig (teacher)
    const float* dten = parity ? d_orig : d_cq;
    const float4* p = reinterpret_cast<const float4*>(
        dten + (size_t)nb * LD * DD + (size_t)row * DD);

    float acc[LQ];
#pragma unroll
    for (int i = 0; i < LQ; ++i) acc[i] = 0.0f;
    float ssq = 0.0f;

#define QSTEP(AV, JOFF)                                                        \
    {                                                                          \
        ssq += AV.x*AV.x + AV.y*AV.y + AV.z*AV.z + AV.w*AV.w;                  \
        _Pragma("unroll")                                                      \
        for (int lq = 0; lq < LQ; ++lq) {                                      \
            float4 qv = *reinterpret_cast<const float4*>(                      \
                &q_lds[lq][h * 16 + (JOFF)]);  /* uniform -> broadcast */      \
            acc[lq] += qv.x*AV.x + qv.y*AV.y + qv.z*AV.z + qv.w*AV.w;          \
        }                                                                      \
    }

#pragma unroll 1
    for (int h = 0; h < 8; ++h) {     // 8 x 64B batches per row
        const float4* pb = p + h * 4;
        float4 a0 = pb[0], a1 = pb[1], a2 = pb[2], a3 = pb[3];
        QSTEP(a0, 0);
        __builtin_amdgcn_sched_barrier(0);
        QSTEP(a1, 4);
        __builtin_amdgcn_sched_barrier(0);
        QSTEP(a2, 8);
        __builtin_amdgcn_sched_barrier(0);
        QSTEP(a3, 12);
    }
#undef QSTEP

    int mk = mask[(size_t)nb * LD + row];   // same mask for both tensors
    float inv = 1.0f / fmaxf(sqrtf(ssq), EPSN);

    int lane = tid & 63, wv = tid >> 6;
    float sel = NEGV;
#pragma unroll
    for (int lq = 0; lq < LQ; ++lq) {
        float s = mk ? acc[lq] * inv : NEGV;
        // reduce over the wave's 32 rows of this parity (bits 1..5)
#pragma unroll
        for (int o = 2; o <= 32; o <<= 1) s = fmaxf(s, __shfl_xor(s, o));
        if ((lane >> 1) == lq) sel = s;   // lane 2*lq+parity keeps (lq, tensor)
    }
    wm[wv][lane] = sel;
    __syncthreads();

    if (tid < 64) {
        float v = wm[0][tid];
#pragma unroll
        for (int w = 1; w < 8; ++w) v = fmaxf(v, wm[w][tid]);
        // sum over lq within parity class
#pragma unroll
        for (int o = 2; o <= 32; o <<= 1) v += __shfl_xor(v, o);
        if (tid < 2)
            scores[tid * (Bq * Nn) + b * Nn + n] = v;
    }
}

// ---------------- Kernel 3: log_softmax + KL ----------------
__global__ void loss_k(const float* __restrict__ scores, float* __restrict__ out) {
    int tid = threadIdx.x;   // 128 threads, one per b
    const float* s = scores + tid * Nn;            // student (cq)
    const float* t = scores + Bq * Nn + tid * Nn;  // teacher (orig)
    float sv[Nn], tv[Nn];
#pragma unroll
    for (int n = 0; n < Nn; ++n) { sv[n] = s[n]; tv[n] = t[n]; }
    float ms = sv[0], mt = tv[0];
#pragma unroll
    for (int n = 1; n < Nn; ++n) { ms = fmaxf(ms, sv[n]); mt = fmaxf(mt, tv[n]); }
    float es = 0.0f, et = 0.0f;
#pragma unroll
    for (int n = 0; n < Nn; ++n) { es += expf(sv[n] - ms); et += expf(tv[n] - mt); }
    float lses = ms + logf(es);
    float lset = mt + logf(et);
    double kl = 0.0;
#pragma unroll
    for (int n = 0; n < Nn; ++n) {
        float lt = tv[n] - lset;
        float ls = sv[n] - lses;
        kl += (double)expf(lt) * ((double)lt - (double)ls);
    }
#pragma unroll
    for (int o = 32; o; o >>= 1) kl += __shfl_xor(kl, o);
    __shared__ double part[2];
    if ((tid & 63) == 0) part[tid >> 6] = kl;
    __syncthreads();
    if (tid == 0) out[0] = (float)((part[0] + part[1]) / (double)Bq);
}

extern "C" void kernel_launch(void* const* d_in, const int* in_sizes, int n_in,
                              void* d_out, int out_size, void* d_ws, size_t ws_size,
                              hipStream_t stream) {
    const float* q     = (const float*)d_in[0];
    const float* dcq   = (const float*)d_in[1];
    const float* dorig = (const float*)d_in[2];
    const int*   mask  = (const int*)d_in[3];
    // labels (d_in[4]) unused by the reference loss path

    float* qn     = (float*)d_ws;                      // [B*LQ*DD] = 2MB
    float* scores = qn + (size_t)Bq * LQ * DD;         // [2][B][N] = 8KB

    qnorm_k<<<(Bq * LQ) / 4, 256, 0, stream>>>(q, qn);
    maxsim_k<<<Nn * Bq, 512, 0, stream>>>(dcq, dorig, mask, qn, scores);
    loss_k<<<1, 128, 0, stream>>>(scores, (float*)d_out);
}